// Round 1
// baseline (181.005 us; speedup 1.0000x reference)
//
#include <hip/hip_runtime.h>

namespace {
constexpr int kB = 1024;
constexpr int kN = 40;
constexpr int kE = 64;
constexpr int kP = kN * (kN - 1) / 2;  // 780

// Transpose inputs (B, N, E) -> (N, E, B) so the main kernel's lane=b loads coalesce.
__global__ void transpose_bne_to_neb(const float* __restrict__ in, float* __restrict__ out) {
  __shared__ float tile[64][65];  // +1 pad: conflict-free read phase
  const int n  = blockIdx.x;        // node
  const int b0 = blockIdx.y * 64;   // batch tile base
  const int t  = threadIdx.x;       // 256 threads
  const int e  = t & 63;
  const int r0 = t >> 6;            // 0..3
#pragma unroll
  for (int k = 0; k < 16; ++k) {
    const int br = r0 + 4 * k;      // batch row within tile
    tile[br][e] = in[(size_t)(b0 + br) * (kN * kE) + n * kE + e];  // coalesced in e
  }
  __syncthreads();
#pragma unroll
  for (int k = 0; k < 16; ++k) {
    const int er = r0 + 4 * k;      // e row
    // lanes read tile[e][er]: bank (e*65+er)%32 = (e+er)%32 -> conflict-free
    out[(size_t)n * kE * kB + (size_t)er * kB + (b0 + e)] = tile[e][er];  // coalesced in b
  }
}

// Lane = batch. M[f,e] is wave-uniform -> s_load + v_fmac with scalar operand.
template <bool TR>
__global__ __launch_bounds__(256, 2) void opn_main(const float* __restrict__ inp,
                                                   const float* __restrict__ param,
                                                   float* __restrict__ out) {
  const int i    = blockIdx.x;                     // pair index, uniform
  const int wave = threadIdx.x >> 6;
  const int lane = threadIdx.x & 63;
  const int b    = (blockIdx.y * 4 + wave) * 64 + lane;  // batch

  // decode pair i -> (r, c), wave-uniform (matches reference row-major pair order)
  int rem = i, r = 0;
  while (rem >= kN - 1 - r) { rem -= kN - 1 - r; ++r; }
  const int c = r + 1 + rem;

  float p[kE];  // 64 VGPRs: p_b vector
  const float* qbase;
  if (TR) {
    const float* pb = inp + (size_t)r * kE * kB + b;   // (N,E,B) layout
    qbase           = inp + (size_t)c * kE * kB + b;
#pragma unroll
    for (int e = 0; e < kE; ++e) p[e] = pb[e * kB];    // coalesced
  } else {
    const float* pb = inp + (size_t)b * (kN * kE) + r * kE;  // direct (B,N,E)
    qbase           = inp + (size_t)b * (kN * kE) + c * kE;
#pragma unroll
    for (int e = 0; e < kE; ++e) p[e] = pb[e];         // per-lane 256B, L1-absorbed
  }

  float acc = 0.f;
  for (int f = 0; f < kE; ++f) {
    const float* Mrow = param + ((size_t)f * kP + i) * kE;  // uniform -> s_load
    float t0 = 0.f, t1 = 0.f, t2 = 0.f, t3 = 0.f;  // break dep chain (4-cyc FMA latency)
#pragma unroll
    for (int e = 0; e < kE; e += 4) {
      t0 = fmaf(Mrow[e + 0], p[e + 0], t0);
      t1 = fmaf(Mrow[e + 1], p[e + 1], t1);
      t2 = fmaf(Mrow[e + 2], p[e + 2], t2);
      t3 = fmaf(Mrow[e + 3], p[e + 3], t3);
    }
    const float qf = TR ? qbase[f * kB] : qbase[f];
    acc = fmaf((t0 + t1) + (t2 + t3), qf, acc);
  }
  // out shape (B, 1, P): scatter store, merged in L2 across i-consecutive blocks
  out[(size_t)b * kP + i] = acc;
}
}  // namespace

extern "C" void kernel_launch(void* const* d_in, const int* in_sizes, int n_in,
                              void* d_out, int out_size, void* d_ws, size_t ws_size,
                              hipStream_t stream) {
  const float* inputs = (const float*)d_in[0];  // (B, N, E) fp32
  const float* param  = (const float*)d_in[1];  // (E, P, E) fp32
  float* out          = (float*)d_out;          // (B, 1, P) fp32

  const size_t need = (size_t)kN * kE * kB * sizeof(float);
  if (ws_size >= need) {
    float* inT = (float*)d_ws;
    transpose_bne_to_neb<<<dim3(kN, kB / 64), 256, 0, stream>>>(inputs, inT);
    opn_main<true><<<dim3(kP, 4), 256, 0, stream>>>(inT, param, out);
  } else {
    opn_main<false><<<dim3(kP, 4), 256, 0, stream>>>(inputs, param, out);
  }
}

// Round 2
// 125.660 us; speedup vs baseline: 1.4404x; 1.4404x over previous
//
#include <hip/hip_runtime.h>

namespace {
constexpr int kB = 1024;
constexpr int kN = 40;
constexpr int kE = 64;
constexpr int kP = kN * (kN - 1) / 2;  // 780

using bf16x8 = __attribute__((ext_vector_type(8))) short;
using f32x4  = __attribute__((ext_vector_type(4))) float;

__device__ inline unsigned short f2bf(float x) {  // RNE fp32->bf16
  union { float f; unsigned u; } v; v.f = x;
  return (unsigned short)((v.u + 0x7FFFu + ((v.u >> 16) & 1u)) >> 16);
}
__device__ inline float bf2f(unsigned short u) {
  union { unsigned u; float f; } v; v.u = (unsigned)u << 16;
  return v.f;
}

// ---- prep: inputs (B,N,E) fp32 -> bf16, same layout ----
__global__ void cvt_inputs_bf16(const float* __restrict__ in, unsigned short* __restrict__ out) {
  const int idx = (blockIdx.x * 256 + threadIdx.x) * 4;
  if (idx + 3 < kB * kN * kE) {
    const float4 v = *(const float4*)(in + idx);
    ushort4 o;
    o.x = f2bf(v.x); o.y = f2bf(v.y); o.z = f2bf(v.z); o.w = f2bf(v.w);
    *(ushort4*)(out + idx) = o;
  }
}

// ---- main: per pair i, S[f,b] = sum_e M[f,e] p[b,e] via MFMA, then VALU dot with q ----
// grid (kP, 2), block 256. Each block: one pair, 512 batches (32 batch-groups of 16).
__global__ __launch_bounds__(256, 2)
void opn_mfma(const unsigned short* __restrict__ xbf,  // (B,N,E) bf16
              const float* __restrict__ param,          // (E,P,E) fp32
              float* __restrict__ outT) {               // (P,B) fp32 intermediate
  const int i    = blockIdx.x;
  const int g    = blockIdx.y;        // 0..1
  const int w    = threadIdx.x >> 6;  // wave 0..3
  const int L    = threadIdx.x & 63;
  const int col  = L & 15;            // MFMA n / col index
  const int quad = L >> 4;            // 0..3

  // pair i -> (r, c), wave-uniform, reference row-major order
  int rem = i, r = 0;
  while (rem >= kN - 1 - r) { rem -= kN - 1 - r; ++r; }
  const int c = r + 1 + rem;

  // A fragments: M_i[f,e], A[m=f][k=e]; lane: m = 16*mt + col, k = quad*8 + j (+32*ks).
  // fp32->bf16 inline: 64 cvts/lane once per block, amortized over 32 batch-groups.
  bf16x8 A[4][2];
#pragma unroll
  for (int mt = 0; mt < 4; ++mt) {
    const float* Mrow = param + ((size_t)(16 * mt + col) * kP + i) * kE + quad * 8;
#pragma unroll
    for (int ks = 0; ks < 2; ++ks) {
      const float4 s0 = *(const float4*)(Mrow + 32 * ks);
      const float4 s1 = *(const float4*)(Mrow + 32 * ks + 4);
      bf16x8 a;
      a[0] = (short)f2bf(s0.x); a[1] = (short)f2bf(s0.y);
      a[2] = (short)f2bf(s0.z); a[3] = (short)f2bf(s0.w);
      a[4] = (short)f2bf(s1.x); a[5] = (short)f2bf(s1.y);
      a[6] = (short)f2bf(s1.z); a[7] = (short)f2bf(s1.w);
      A[mt][ks] = a;
    }
  }

  // 2 store-groups of 64 batches each (4 batch-groups of 16)
#pragma unroll
  for (int sg = 0; sg < 2; ++sg) {
    const int B0 = (g * 8 + w * 2 + sg) * 64;
    float dots[4];
#pragma unroll
    for (int t = 0; t < 4; ++t) {
      const int b = B0 + 16 * t + col;  // this lane's batch (MFMA col)
      // B fragments: p[b,e] = xbf[b,r,e]; B[k=e][n=b]; lane: n=col, k=quad*8+j (+32*ks)
      const unsigned short* pb = xbf + ((size_t)b * kN + r) * kE + quad * 8;
      bf16x8 Bf0 = *(const bf16x8*)(pb);
      bf16x8 Bf1 = *(const bf16x8*)(pb + 32);

      f32x4 acc[4];
#pragma unroll
      for (int mt = 0; mt < 4; ++mt) acc[mt] = (f32x4){0.f, 0.f, 0.f, 0.f};
#pragma unroll
      for (int mt = 0; mt < 4; ++mt) {
        acc[mt] = __builtin_amdgcn_mfma_f32_16x16x32_bf16(A[mt][0], Bf0, acc[mt], 0, 0, 0);
        acc[mt] = __builtin_amdgcn_mfma_f32_16x16x32_bf16(A[mt][1], Bf1, acc[mt], 0, 0, 0);
      }
      // dot with q: lane holds S[f,b] for f = 16*mt + quad*4 + reg
      const unsigned short* qb = xbf + ((size_t)b * kN + c) * kE + quad * 4;
      float dot = 0.f;
#pragma unroll
      for (int mt = 0; mt < 4; ++mt) {
        const ushort4 qu = *(const ushort4*)(qb + 16 * mt);
        dot = fmaf(acc[mt][0], bf2f(qu.x), dot);
        dot = fmaf(acc[mt][1], bf2f(qu.y), dot);
        dot = fmaf(acc[mt][2], bf2f(qu.z), dot);
        dot = fmaf(acc[mt][3], bf2f(qu.w), dot);
      }
      // reduce over the 4 lanes (stride 16) sharing this batch column
      dot += __shfl_xor(dot, 16, 64);
      dot += __shfl_xor(dot, 32, 64);
      dots[t] = dot;
    }
    // lane L stores b = B0 + L: pick dots[quad] (uniform across the col-sharing lanes)
    float v = dots[0];
    v = (quad == 1) ? dots[1] : v;
    v = (quad == 2) ? dots[2] : v;
    v = (quad == 3) ? dots[3] : v;
    outT[(size_t)i * kB + B0 + L] = v;  // coalesced 256 B per wave
  }
}

// ---- transpose (P,B) -> (B,P) ----
__global__ void transpose_pb_to_bp(const float* __restrict__ in, float* __restrict__ out) {
  __shared__ float tile[64][65];
  const int p0 = blockIdx.x * 64;
  const int b0 = blockIdx.y * 64;
  const int t  = threadIdx.x;
  const int x  = t & 63;
  const int y0 = t >> 6;
#pragma unroll
  for (int k = 0; k < 16; ++k) {
    const int p = p0 + y0 + 4 * k;
    if (p < kP) tile[y0 + 4 * k][x] = in[(size_t)p * kB + b0 + x];
  }
  __syncthreads();
#pragma unroll
  for (int k = 0; k < 16; ++k) {
    const int br = y0 + 4 * k;
    if (p0 + x < kP) out[(size_t)(b0 + br) * kP + p0 + x] = tile[x][br];
  }
}

// ---- fallback (no ws): round-0 fp32 path, correct without scratch ----
__global__ __launch_bounds__(256, 2)
void opn_fp32(const float* __restrict__ inp, const float* __restrict__ param,
              float* __restrict__ out) {
  const int i    = blockIdx.x;
  const int wave = threadIdx.x >> 6;
  const int lane = threadIdx.x & 63;
  const int b    = (blockIdx.y * 4 + wave) * 64 + lane;
  int rem = i, r = 0;
  while (rem >= kN - 1 - r) { rem -= kN - 1 - r; ++r; }
  const int c = r + 1 + rem;
  const float* pb = inp + (size_t)b * (kN * kE) + r * kE;
  const float* qb = inp + (size_t)b * (kN * kE) + c * kE;
  float p[kE];
#pragma unroll
  for (int e = 0; e < kE; ++e) p[e] = pb[e];
  float acc = 0.f;
  for (int f = 0; f < kE; ++f) {
    const float* Mrow = param + ((size_t)f * kP + i) * kE;
    float t0 = 0.f, t1 = 0.f, t2 = 0.f, t3 = 0.f;
#pragma unroll
    for (int e = 0; e < kE; e += 4) {
      t0 = fmaf(Mrow[e + 0], p[e + 0], t0);
      t1 = fmaf(Mrow[e + 1], p[e + 1], t1);
      t2 = fmaf(Mrow[e + 2], p[e + 2], t2);
      t3 = fmaf(Mrow[e + 3], p[e + 3], t3);
    }
    acc = fmaf((t0 + t1) + (t2 + t3), qb[f], acc);
  }
  out[(size_t)b * kP + i] = acc;
}
}  // namespace

extern "C" void kernel_launch(void* const* d_in, const int* in_sizes, int n_in,
                              void* d_out, int out_size, void* d_ws, size_t ws_size,
                              hipStream_t stream) {
  const float* inputs = (const float*)d_in[0];  // (B, N, E) fp32
  const float* param  = (const float*)d_in[1];  // (E, P, E) fp32
  float* out          = (float*)d_out;          // (B, 1, P) fp32

  const size_t xbf_bytes  = (size_t)kB * kN * kE * sizeof(unsigned short);  // 5.24 MB
  const size_t outT_bytes = (size_t)kP * kB * sizeof(float);                // 3.19 MB

  if (ws_size >= xbf_bytes + outT_bytes) {
    unsigned short* xbf = (unsigned short*)d_ws;
    float* outT         = (float*)((char*)d_ws + xbf_bytes);
    cvt_inputs_bf16<<<(kB * kN * kE) / (256 * 4), 256, 0, stream>>>(inputs, xbf);
    opn_mfma<<<dim3(kP, 2), 256, 0, stream>>>(xbf, param, outT);
    transpose_pb_to_bp<<<dim3((kP + 63) / 64, kB / 64), 256, 0, stream>>>(outT, out);
  } else {
    opn_fp32<<<dim3(kP, 4), 256, 0, stream>>>(inputs, param, out);
  }
}

// Round 3
// 120.480 us; speedup vs baseline: 1.5024x; 1.0430x over previous
//
#include <hip/hip_runtime.h>

namespace {
constexpr int kB = 1024;
constexpr int kN = 40;
constexpr int kE = 64;
constexpr int kP = kN * (kN - 1) / 2;  // 780

using bf16x8 = __attribute__((ext_vector_type(8))) short;
using f32x4  = __attribute__((ext_vector_type(4))) float;

__device__ inline unsigned short f2bf(float x) {  // RNE fp32->bf16
  union { float f; unsigned u; } v; v.f = x;
  return (unsigned short)((v.u + 0x7FFFu + ((v.u >> 16) & 1u)) >> 16);
}
__device__ inline float bf2f(unsigned short u) {
  union { unsigned u; float f; } v; v.u = (unsigned)u << 16;
  return v.f;
}

// ---- inputs (B,N,E) fp32 -> xT (N,B,E) bf16: makes main-kernel b-gathers land
// in contiguous 2KB windows instead of 5KB-strided 16-line gathers.
__global__ __launch_bounds__(256) void cvt_transpose(const float* __restrict__ in,
                                                     unsigned short* __restrict__ xT) {
  const int n  = blockIdx.x;
  const int b0 = blockIdx.y * 128;
  const int t  = threadIdx.x;
#pragma unroll
  for (int rep = 0; rep < 2; ++rep) {
    const int b  = b0 + rep * 64 + (t >> 2);
    const int ch = (t & 3) * 16;
    const float* src = in + ((size_t)b * kN + n) * kE + ch;      // 256B/row, 4 lanes/row
    unsigned short* dst = xT + ((size_t)n * kB + b) * kE + ch;   // contiguous across t
    const float4 v0 = ((const float4*)src)[0];
    const float4 v1 = ((const float4*)src)[1];
    const float4 v2 = ((const float4*)src)[2];
    const float4 v3 = ((const float4*)src)[3];
    ushort4 o0, o1, o2, o3;
    o0.x = f2bf(v0.x); o0.y = f2bf(v0.y); o0.z = f2bf(v0.z); o0.w = f2bf(v0.w);
    o1.x = f2bf(v1.x); o1.y = f2bf(v1.y); o1.z = f2bf(v1.z); o1.w = f2bf(v1.w);
    o2.x = f2bf(v2.x); o2.y = f2bf(v2.y); o2.z = f2bf(v2.z); o2.w = f2bf(v2.w);
    o3.x = f2bf(v3.x); o3.y = f2bf(v3.y); o3.z = f2bf(v3.z); o3.w = f2bf(v3.w);
    ((ushort4*)dst)[0] = o0; ((ushort4*)dst)[1] = o1;
    ((ushort4*)dst)[2] = o2; ((ushort4*)dst)[3] = o3;
  }
}

// ---- main: block = one pair i x all 1024 batches; 512 threads (8 waves).
// S[f,b] = sum_e M_i[f,e] p[b,e] via mfma_16x16x32_bf16 (layouts HW-verified in R2),
// then per-lane fp32 dot with q + 2 shfl_xor reduce.
__global__ __launch_bounds__(512, 4)
void opn_mfma(const unsigned short* __restrict__ xT,  // (N,B,E) bf16
              const float* __restrict__ param,         // (E,P,E) fp32
              float* __restrict__ outT) {               // (P,B) fp32
  __shared__ short Ms[64 * 72];  // stride 72 shorts: 2-way-free bank pattern

  const int i    = blockIdx.x;
  const int t    = threadIdx.x;
  const int w    = t >> 6;
  const int L    = t & 63;
  const int col  = L & 15;
  const int quad = L >> 4;

  // pair i -> (r, c), reference row-major order (wave-uniform scalar loop)
  int rem = i, r = 0;
  while (rem >= kN - 1 - r) { rem -= kN - 1 - r; ++r; }
  const int c = r + 1 + rem;

  // stage M_i coalesced: 64 f-rows x 256B contiguous, cvt to bf16 in LDS
  {
    const int f  = t >> 3;
    const int ch = (t & 7) * 8;
    const float* src = param + ((size_t)f * kP + i) * kE + ch;
    const float4 v0 = ((const float4*)src)[0];
    const float4 v1 = ((const float4*)src)[1];
    bf16x8 m;
    m[0] = (short)f2bf(v0.x); m[1] = (short)f2bf(v0.y);
    m[2] = (short)f2bf(v0.z); m[3] = (short)f2bf(v0.w);
    m[4] = (short)f2bf(v1.x); m[5] = (short)f2bf(v1.y);
    m[6] = (short)f2bf(v1.z); m[7] = (short)f2bf(v1.w);
    *(bf16x8*)(&Ms[f * 72 + ch]) = m;
  }
  __syncthreads();

  // A-frags from LDS: A[m=f=16mt+col][k=e=quad*8+j+32ks]
  bf16x8 A[4][2];
#pragma unroll
  for (int mt = 0; mt < 4; ++mt)
#pragma unroll
    for (int ks = 0; ks < 2; ++ks)
      A[mt][ks] = *(const bf16x8*)(&Ms[(16 * mt + col) * 72 + ks * 32 + quad * 8]);

  const unsigned short* prow = xT + (size_t)r * kB * kE;
  const unsigned short* qrow = xT + (size_t)c * kB * kE;

#pragma unroll
  for (int j = 0; j < 4; ++j) {
    const int b0 = w * 128 + j * 32;
    float d[2];
#pragma unroll
    for (int h = 0; h < 2; ++h) {
      const int b = b0 + h * 16 + col;
      // B-frag: p[b][e], lanes stride 128B -> 2KB contiguous window
      const unsigned short* pb = prow + (size_t)b * kE + quad * 8;
      const bf16x8 Bf0 = *(const bf16x8*)(pb);
      const bf16x8 Bf1 = *(const bf16x8*)(pb + 32);
      // q[b][f] for this lane's acc rows f = 16mt + quad*4 + reg
      const unsigned short* qb = qrow + (size_t)b * kE + quad * 4;
      const ushort4 q0 = *(const ushort4*)(qb);
      const ushort4 q1 = *(const ushort4*)(qb + 16);
      const ushort4 q2 = *(const ushort4*)(qb + 32);
      const ushort4 q3 = *(const ushort4*)(qb + 48);

      f32x4 acc[4];
#pragma unroll
      for (int mt = 0; mt < 4; ++mt) acc[mt] = (f32x4){0.f, 0.f, 0.f, 0.f};
#pragma unroll
      for (int mt = 0; mt < 4; ++mt) {
        acc[mt] = __builtin_amdgcn_mfma_f32_16x16x32_bf16(A[mt][0], Bf0, acc[mt], 0, 0, 0);
        acc[mt] = __builtin_amdgcn_mfma_f32_16x16x32_bf16(A[mt][1], Bf1, acc[mt], 0, 0, 0);
      }
      float dot = 0.f;
      dot = fmaf(acc[0][0], bf2f(q0.x), dot); dot = fmaf(acc[0][1], bf2f(q0.y), dot);
      dot = fmaf(acc[0][2], bf2f(q0.z), dot); dot = fmaf(acc[0][3], bf2f(q0.w), dot);
      dot = fmaf(acc[1][0], bf2f(q1.x), dot); dot = fmaf(acc[1][1], bf2f(q1.y), dot);
      dot = fmaf(acc[1][2], bf2f(q1.z), dot); dot = fmaf(acc[1][3], bf2f(q1.w), dot);
      dot = fmaf(acc[2][0], bf2f(q2.x), dot); dot = fmaf(acc[2][1], bf2f(q2.y), dot);
      dot = fmaf(acc[2][2], bf2f(q2.z), dot); dot = fmaf(acc[2][3], bf2f(q2.w), dot);
      dot = fmaf(acc[3][0], bf2f(q3.x), dot); dot = fmaf(acc[3][1], bf2f(q3.y), dot);
      dot = fmaf(acc[3][2], bf2f(q3.z), dot); dot = fmaf(acc[3][3], bf2f(q3.w), dot);
      dot += __shfl_xor(dot, 16, 64);
      dot += __shfl_xor(dot, 32, 64);
      d[h] = dot;  // replicated across quads
    }
    // half-wave 128B contiguous store: lane L<32 -> batch b0+L
    if (L < 32) outT[(size_t)i * kB + b0 + L] = (L & 16) ? d[1] : d[0];
  }
}

// ---- transpose (P,B) -> (B,P) ----
__global__ void transpose_pb_to_bp(const float* __restrict__ in, float* __restrict__ out) {
  __shared__ float tile[64][65];
  const int p0 = blockIdx.x * 64;
  const int b0 = blockIdx.y * 64;
  const int t  = threadIdx.x;
  const int x  = t & 63;
  const int y0 = t >> 6;
#pragma unroll
  for (int k = 0; k < 16; ++k) {
    const int p = p0 + y0 + 4 * k;
    if (p < kP) tile[y0 + 4 * k][x] = in[(size_t)p * kB + b0 + x];
  }
  __syncthreads();
#pragma unroll
  for (int k = 0; k < 16; ++k) {
    const int br = y0 + 4 * k;
    if (p0 + x < kP) out[(size_t)(b0 + br) * kP + p0 + x] = tile[x][br];
  }
}

// ---- fallback (no ws): fp32 path ----
__global__ __launch_bounds__(256, 2)
void opn_fp32(const float* __restrict__ inp, const float* __restrict__ param,
              float* __restrict__ out) {
  const int i    = blockIdx.x;
  const int wave = threadIdx.x >> 6;
  const int lane = threadIdx.x & 63;
  const int b    = (blockIdx.y * 4 + wave) * 64 + lane;
  int rem = i, r = 0;
  while (rem >= kN - 1 - r) { rem -= kN - 1 - r; ++r; }
  const int c = r + 1 + rem;
  const float* pb = inp + (size_t)b * (kN * kE) + r * kE;
  const float* qb = inp + (size_t)b * (kN * kE) + c * kE;
  float p[kE];
#pragma unroll
  for (int e = 0; e < kE; ++e) p[e] = pb[e];
  float acc = 0.f;
  for (int f = 0; f < kE; ++f) {
    const float* Mrow = param + ((size_t)f * kP + i) * kE;
    float t0 = 0.f, t1 = 0.f, t2 = 0.f, t3 = 0.f;
#pragma unroll
    for (int e = 0; e < kE; e += 4) {
      t0 = fmaf(Mrow[e + 0], p[e + 0], t0);
      t1 = fmaf(Mrow[e + 1], p[e + 1], t1);
      t2 = fmaf(Mrow[e + 2], p[e + 2], t2);
      t3 = fmaf(Mrow[e + 3], p[e + 3], t3);
    }
    acc = fmaf((t0 + t1) + (t2 + t3), qb[f], acc);
  }
  out[(size_t)b * kP + i] = acc;
}
}  // namespace

extern "C" void kernel_launch(void* const* d_in, const int* in_sizes, int n_in,
                              void* d_out, int out_size, void* d_ws, size_t ws_size,
                              hipStream_t stream) {
  const float* inputs = (const float*)d_in[0];  // (B, N, E) fp32
  const float* param  = (const float*)d_in[1];  // (E, P, E) fp32
  float* out          = (float*)d_out;          // (B, 1, P) fp32

  const size_t xT_bytes   = (size_t)kN * kB * kE * sizeof(unsigned short);  // 5.24 MB
  const size_t outT_bytes = (size_t)kP * kB * sizeof(float);                // 3.19 MB

  if (ws_size >= xT_bytes + outT_bytes) {
    unsigned short* xT = (unsigned short*)d_ws;
    float* outT        = (float*)((char*)d_ws + xT_bytes);
    cvt_transpose<<<dim3(kN, kB / 128), 256, 0, stream>>>(inputs, xT);
    opn_mfma<<<kP, 512, 0, stream>>>(xT, param, outT);
    transpose_pb_to_bp<<<dim3((kP + 63) / 64, kB / 64), 256, 0, stream>>>(outT, out);
  } else {
    opn_fp32<<<dim3(kP, 4), 256, 0, stream>>>(inputs, param, out);
  }
}